// Round 3
// baseline (157.981 us; speedup 1.0000x reference)
//
#include <hip/hip_runtime.h>

// Signature-kernel MMD via Goursat PDE — round 3.
// R2 postmortem: DPP scan + SGPR dX got pde to 94us but VALUBusy stuck at 66%
// -> latency-bound on the ~40cyc/row loop-carried scan chain with only ~3.8
// waves/SIMD. R3: (1) 2 PDE pairs per wave (same row-path a), interleaved ->
// 2x ILP, shared SGPR dX row; exactly 4160 wave-duos = 1040 blocks x 4 waves,
// zero idle slots. (2) 2-row unrolled K-loop with alternating SGPR x-buffers
// (no per-row s_mov copies, s_load prefetch 1 row ahead). (3) reduction fused:
// LDS 4-slot block reduce + one atomicAdd per block; d_out zeroed in sig_diff.

#define DINC_PER 130048                         // 64*127*16 floats
#define NDUO 4160                               // 2048 XY + 2*1056 tri duos
#define NBLOCKS (NDUO / 4)                      // 1040

template <int C, int RM, int BM, bool BC>
__device__ __forceinline__ float dpp0(float x) {
    return __builtin_bit_cast(float, __builtin_amdgcn_update_dpp(
        0, __builtin_bit_cast(int, x), C, RM, BM, BC));
}

// 64-lane inclusive prefix sum, pure VALU (6 dependent adds).
__device__ __forceinline__ float wave_scan_incl(float v) {
    v += dpp0<0x111, 0xf, 0xf, true>(v);   // row_shr:1
    v += dpp0<0x112, 0xf, 0xf, true>(v);   // row_shr:2
    v += dpp0<0x114, 0xf, 0xf, true>(v);   // row_shr:4
    v += dpp0<0x118, 0xf, 0xf, true>(v);   // row_shr:8
    v += dpp0<0x142, 0xa, 0xf, false>(v);  // row_bcast:15 -> rows 1,3
    v += dpp0<0x143, 0xc, 0xf, false>(v);  // row_bcast:31 -> rows 2,3
    return v;
}

// lane l gets lane l-1's x; lane 0 gets `oldv`.
__device__ __forceinline__ float wave_shr1(float x, float oldv) {
    return __builtin_bit_cast(float, __builtin_amdgcn_update_dpp(
        __builtin_bit_cast(int, oldv), __builtin_bit_cast(int, x),
        0x138, 0xf, 0xf, false));          // wave_shr:1
}

// one PDE row for one pair; xr is the (wave-uniform, SGPR) dX row
__device__ __forceinline__ void pde_row(
    const float* xr, const float* ya, const float* yb,
    float& g_lo, float& g_hi, int lane)
{
    float s0 = -0.5f, s1 = -0.5f, t0 = -0.5f, t1 = -0.5f;
#pragma unroll
    for (int d = 0; d < 16; d += 2) {
        s0 = fmaf(xr[d], ya[d], s0);    s1 = fmaf(xr[d+1], ya[d+1], s1);
        t0 = fmaf(xr[d], yb[d], t0);    t1 = fmaf(xr[d+1], yb[d+1], t1);
    }
    const float i0 = s0 + s1;                      // inc(r,2l)   - 1
    const float i1 = t0 + t1;                      // inc(r,2l+1) - 1
    const float gl = wave_shr1(g_hi, 1.0f);        // G[r][2l], lane0 -> 1
    const float c0 = fmaf(gl, i0, g_lo);
    const float c1 = (lane == 63) ? 0.0f : fmaf(g_lo, i1, g_hi);
    const float S = wave_scan_incl(c0 + c1);
    g_lo = (S - c1) + 1.0f;
    g_hi = S + 1.0f;
}

__device__ __forceinline__ void load_xrow(float* x, const float4* Ar, int r) {
#pragma unroll
    for (int q = 0; q < 4; ++q) {
        float4 v = Ar[4 * r + q];
        x[4*q+0] = v.x; x[4*q+1] = v.y; x[4*q+2] = v.z; x[4*q+3] = v.w;
    }
}

// ---- kernel 1: path increments X,Y -> ws; also zeroes d_out ----
__global__ __launch_bounds__(256) void sig_diff(
    const float* __restrict__ X, const float* __restrict__ Y,
    float* __restrict__ dInc, float* __restrict__ outp)
{
    if (blockIdx.x == 0 && threadIdx.x == 0) outp[0] = 0.0f;
    int i = blockIdx.x * 256 + threadIdx.x;   // float4 id, 65024 total
    if (i >= 65024) return;
    int which = (i >= 32512) ? 1 : 0;
    int j = i - which * 32512;
    int a = j / 508;                          // 127*4 float4 per path
    int rq = j - a * 508;
    const float* S = which ? Y : X;
    const float4* p = (const float4*)(S + a * 2048) + rq;
    float4 v0 = p[0], v1 = p[4];
    float4 d;
    d.x = v1.x - v0.x; d.y = v1.y - v0.y;
    d.z = v1.z - v0.z; d.w = v1.w - v0.w;
    ((float4*)dInc)[i] = d;
}

// ---- kernel 2: PDE, 2 pairs per wave (same a), fused block reduction ----
__global__ __launch_bounds__(256) void sig_pde3(
    const float* __restrict__ dInc, float* __restrict__ outp)
{
    __shared__ float red[4];
    const int wv = threadIdx.x >> 6, lane = threadIdx.x & 63;
    const int T = (blockIdx.x << 2) + wv;     // wave duo-task id, 0..4159

    int g, a, b1, b2;
    float w1, w2;
    if (T < 2048) {                            // XY gram: dense
        g = 2; a = T >> 5;
        b1 = (T & 31) << 1; b2 = b1 + 1;
        w1 = w2 = -2.0f / 4096.0f;
    } else {                                   // XX / YY: upper triangle
        int t = T - 2048;
        g = (t >= 1056) ? 1 : 0;
        if (g) t -= 1056;
        int aa = 0;
        for (;;) { int nd = (65 - aa) >> 1; if (t < nd) break; t -= nd; ++aa; }
        a = aa; b1 = a + (t << 1); b2 = b1 + 1;
        w1 = (b1 == a ? 1.0f : 2.0f) / 4096.0f;
        w2 = (b2 <= 63) ? (2.0f / 4096.0f) : 0.0f;
        if (b2 > 63) b2 = 63;                  // masked via w2=0
    }

    const float* dA = (g == 1) ? (dInc + DINC_PER) : dInc;   // row paths
    const float* dB = (g == 0) ? dInc : (dInc + DINC_PER);   // col paths

    // per-lane dY rows j=2l, 2l+1 for both pairs
    float yaA[16], ybA[16], yaB[16], ybB[16];
    {
        const int j0 = lane << 1;
        const int j1 = (j0 + 1 < 127) ? j0 + 1 : 126;  // lane63 clamp (masked)
        const float4* A4 = (const float4*)(dB + b1 * 2032 + j0 * 16);
        const float4* B4 = (const float4*)(dB + b1 * 2032 + j1 * 16);
        const float4* C4 = (const float4*)(dB + b2 * 2032 + j0 * 16);
        const float4* D4 = (const float4*)(dB + b2 * 2032 + j1 * 16);
#pragma unroll
        for (int q = 0; q < 4; ++q) {
            float4 va = A4[q], vb = B4[q], vc = C4[q], vd = D4[q];
            yaA[4*q+0]=va.x; yaA[4*q+1]=va.y; yaA[4*q+2]=va.z; yaA[4*q+3]=va.w;
            ybA[4*q+0]=vb.x; ybA[4*q+1]=vb.y; ybA[4*q+2]=vb.z; ybA[4*q+3]=vb.w;
            yaB[4*q+0]=vc.x; yaB[4*q+1]=vc.y; yaB[4*q+2]=vc.z; yaB[4*q+3]=vc.w;
            ybB[4*q+0]=vd.x; ybB[4*q+1]=vd.y; ybB[4*q+2]=vd.z; ybB[4*q+3]=vd.w;
        }
    }

    // wave-uniform dX base -> scalar loads
    const int abase = __builtin_amdgcn_readfirstlane(a * 2032);
    const float4* Ar = (const float4*)(dA + abase);

    float xA[16], xB[16];
    load_xrow(xA, Ar, 0);

    float gl1 = 1.0f, gh1 = 1.0f, gl2 = 1.0f, gh2 = 1.0f;

    for (int r = 0; r < 126; r += 2) {
        load_xrow(xB, Ar, r + 1);              // prefetch next row
        pde_row(xA, yaA, ybA, gl1, gh1, lane);
        pde_row(xA, yaB, ybB, gl2, gh2, lane);
        load_xrow(xA, Ar, r + 2);              // prefetch row after
        pde_row(xB, yaA, ybA, gl1, gh1, lane);
        pde_row(xB, yaB, ybB, gl2, gh2, lane);
    }
    // row 126 (xA holds it)
    pde_row(xA, yaA, ybA, gl1, gh1, lane);
    pde_row(xA, yaB, ybB, gl2, gh2, lane);

    const float k1 = __builtin_bit_cast(float,
        __builtin_amdgcn_readlane(__builtin_bit_cast(int, gl1), 63));
    const float k2 = __builtin_bit_cast(float,
        __builtin_amdgcn_readlane(__builtin_bit_cast(int, gl2), 63));
    if (lane == 0) red[wv] = fmaf(w1, k1, w2 * k2);
    __syncthreads();
    if (threadIdx.x == 0)
        atomicAdd(outp, (red[0] + red[1]) + (red[2] + red[3]));
}

// ---- fallback path (tiny ws): round-1-style, self-contained ----
__global__ __launch_bounds__(64) void sig_pde_kernel(
    const float* __restrict__ X, const float* __restrict__ Y,
    float* __restrict__ ws)
{
    __shared__ float Xs[2048];
    const int T = blockIdx.x;
    const int g = T >> 12;
    const int t = T & 4095;
    const int a = t >> 6, b = t & 63;
    const int lane = threadIdx.x;
    if (g < 2 && a > b) { if (lane == 0) ws[T] = 0.0f; return; }
    const float* P = (g == 1) ? Y : X;
    const float* Q = (g == 0) ? X : Y;
    const float weight = (g == 2) ? (-2.0f / 4096.0f)
                                  : ((a == b ? 1.0f : 2.0f) / 4096.0f);
    {
        const float4* Pa = (const float4*)(P + a * 2048);
        float4* Xs4 = (float4*)Xs;
#pragma unroll
        for (int k = 0; k < 8; ++k) Xs4[lane + (k << 6)] = Pa[lane + (k << 6)];
    }
    __syncthreads();
    {
        float tmp[32];
#pragma unroll
        for (int k = 0; k < 32; ++k) {
            int idx = lane + (k << 6);
            tmp[k] = (idx < 2032) ? (Xs[idx + 16] - Xs[idx]) : 0.0f;
        }
        __syncthreads();
#pragma unroll
        for (int k = 0; k < 32; ++k) {
            int idx = lane + (k << 6);
            if (idx < 2032) Xs[idx] = tmp[k];
        }
    }
    __syncthreads();
    float y0[16], y1[16];
    {
        const float* Qb = Q + b * 2048;
        const int r0 = lane << 1;
        const int r2 = (r0 + 2 > 127) ? 127 : (r0 + 2);
        const float4* A4 = (const float4*)(Qb + r0 * 16);
        const float4* B4 = (const float4*)(Qb + (r0 + 1) * 16);
        const float4* C4 = (const float4*)(Qb + r2 * 16);
#pragma unroll
        for (int q = 0; q < 4; ++q) {
            float4 ra = A4[q], rb = B4[q], rc = C4[q];
            y0[4*q+0] = rb.x - ra.x;  y1[4*q+0] = rc.x - rb.x;
            y0[4*q+1] = rb.y - ra.y;  y1[4*q+1] = rc.y - rb.y;
            y0[4*q+2] = rb.z - ra.z;  y1[4*q+2] = rc.z - rb.z;
            y0[4*q+3] = rb.w - ra.w;  y1[4*q+3] = rc.w - rb.w;
        }
    }
    float g_lo = 1.0f, g_hi = 1.0f;
    for (int r = 0; r < 127; ++r) {
        const float* xrow = Xs + r * 16;
        pde_row(xrow, y0, y1, g_lo, g_hi, lane);
    }
    const float kab = __builtin_bit_cast(float,
        __builtin_amdgcn_readlane(__builtin_bit_cast(int, g_lo), 63));
    if (lane == 0) ws[T] = weight * kab;
}

__global__ __launch_bounds__(256) void sig_reduce2(
    const float* __restrict__ v, float* __restrict__ out, int n)
{
    __shared__ float red[256];
    float s = 0.0f;
    for (int i = threadIdx.x; i < n; i += 256) s += v[i];
    red[threadIdx.x] = s;
    __syncthreads();
    for (int st = 128; st > 0; st >>= 1) {
        if (threadIdx.x < st) red[threadIdx.x] += red[threadIdx.x + st];
        __syncthreads();
    }
    if (threadIdx.x == 0) out[0] = red[0];
}

extern "C" void kernel_launch(void* const* d_in, const int* in_sizes, int n_in,
                              void* d_out, int out_size, void* d_ws, size_t ws_size,
                              hipStream_t stream) {
    const float* X = (const float*)d_in[0];
    const float* Y = (const float*)d_in[1];
    float* out = (float*)d_out;
    float* ws  = (float*)d_ws;

    if (ws_size >= (size_t)(2 * DINC_PER) * sizeof(float)) {
        sig_diff<<<254, 256, 0, stream>>>(X, Y, ws, out);
        sig_pde3<<<NBLOCKS, 256, 0, stream>>>(ws, out);
    } else {
        sig_pde_kernel<<<12288, 64, 0, stream>>>(X, Y, ws);
        sig_reduce2<<<1, 256, 0, stream>>>(ws, out, 12288);
    }
}

// Round 4
// 155.006 us; speedup vs baseline: 1.0192x; 1.0192x over previous
//
#include <hip/hip_runtime.h>

// Signature-kernel MMD via Goursat PDE — round 4.
// R3 postmortem: 2 pairs/wave halved wave count (4160 < 8192 slots) ->
// occupancy 24.6%, net regression. 8256 tasks at 1 pair/wave fills the
// machine exactly: keep R2's loop/grid. R4: (1) single kernel — the
// q-difference trick inc(r,j) = dot(x_{r+1},dy)-dot(x_r,dy) lets the PDE
// read RAW X via wave-uniform scalar loads (no diff pass, no LDS); dY
// diffed inline from raw Y; fused block reduce + atomicAdd; d_out zeroed
// by a memset node. 3 launches -> 1. (2) packed-fp32 dots: float2 +
// __builtin_elementwise_fma -> v_pk_fma_f32, 32 FMA/row -> 16 pk ops.

typedef float f2 __attribute__((ext_vector_type(2)));

#define XY_BLOCKS 1024
#define TRI_BLOCKS 544
#define NBLOCKS (XY_BLOCKS + 2 * TRI_BLOCKS)   // 2112 blocks x 4 waves

template <int C, int RM, int BM, bool BC>
__device__ __forceinline__ float dpp0(float x) {
    return __builtin_bit_cast(float, __builtin_amdgcn_update_dpp(
        0, __builtin_bit_cast(int, x), C, RM, BM, BC));
}

// 64-lane inclusive prefix sum, pure VALU (6 dependent adds).
__device__ __forceinline__ float wave_scan_incl(float v) {
    v += dpp0<0x111, 0xf, 0xf, true>(v);   // row_shr:1
    v += dpp0<0x112, 0xf, 0xf, true>(v);   // row_shr:2
    v += dpp0<0x114, 0xf, 0xf, true>(v);   // row_shr:4
    v += dpp0<0x118, 0xf, 0xf, true>(v);   // row_shr:8
    v += dpp0<0x142, 0xa, 0xf, false>(v);  // row_bcast:15 -> rows 1,3
    v += dpp0<0x143, 0xc, 0xf, false>(v);  // row_bcast:31 -> rows 2,3
    return v;
}

// lane l gets lane l-1's x; lane 0 gets `oldv`.
__device__ __forceinline__ float wave_shr1(float x, float oldv) {
    return __builtin_bit_cast(float, __builtin_amdgcn_update_dpp(
        __builtin_bit_cast(int, oldv), __builtin_bit_cast(int, x),
        0x138, 0xf, 0xf, false));          // wave_shr:1
}

// raw X row r (wave-uniform addr -> s_load) into 8 float2
__device__ __forceinline__ void load_xrow(f2* x, const float4* Ar, int r) {
#pragma unroll
    for (int q = 0; q < 4; ++q) {
        float4 v = Ar[4 * r + q];
        x[2*q].x   = v.x; x[2*q].y   = v.y;
        x[2*q+1].x = v.z; x[2*q+1].y = v.w;
    }
}

// One PDE row. xr = RAW x_{r+1} (8 f2). qpA/qpB = dot(x_r, y)+1 carried in.
__device__ __forceinline__ void pde_row(
    const f2* xr, const f2* ya, const f2* yb,
    float& qpA, float& qpB, float& g_lo, float& g_hi, int lane)
{
    f2 s0 = 0.0f, s1 = 0.0f, t0 = 0.0f, t1 = 0.0f;
#pragma unroll
    for (int d = 0; d < 8; d += 2) {
        s0 = __builtin_elementwise_fma(xr[d],   ya[d],   s0);
        s1 = __builtin_elementwise_fma(xr[d+1], ya[d+1], s1);
        t0 = __builtin_elementwise_fma(xr[d],   yb[d],   t0);
        t1 = __builtin_elementwise_fma(xr[d+1], yb[d+1], t1);
    }
    const f2 sA = s0 + s1, sB = t0 + t1;
    const float hA = sA.x + sA.y, hB = sB.x + sB.y;  // dot(x_{r+1}, y)
    const float i0 = hA - qpA;  qpA = hA + 1.0f;     // inc(r,2l)-1
    const float i1 = hB - qpB;  qpB = hB + 1.0f;     // inc(r,2l+1)-1
    const float gl = wave_shr1(g_hi, 1.0f);          // G[r][2l], lane0 -> 1
    const float c0 = fmaf(gl, i0, g_lo);
    const float c1 = (lane == 63) ? 0.0f : fmaf(g_lo, i1, g_hi);
    const float S = wave_scan_incl(c0 + c1);
    g_lo = (S - c1) + 1.0f;
    g_hi = S + 1.0f;
}

__global__ __launch_bounds__(256) void sig_pde4(
    const float* __restrict__ X, const float* __restrict__ Y,
    float* __restrict__ outp)
{
    __shared__ float red[4];
    const int wv = threadIdx.x >> 6, lane = threadIdx.x & 63;
    const int B = blockIdx.x;

    int g, a, b;
    if (B < XY_BLOCKS) {                       // XY gram: dense 64x64
        g = 2; a = B >> 4; b = ((B & 15) << 2) + wv;
    } else {                                   // XX / YY: upper triangle
        int t = B - XY_BLOCKS; g = 0;
        if (t >= TRI_BLOCKS) { t -= TRI_BLOCKS; g = 1; }
        int aa = 0;
        for (;;) { int nb = (67 - aa) >> 2; if (t < nb) break; t -= nb; ++aa; }
        a = aa; b = aa + (t << 2) + wv;
    }
    float weight = (g == 2) ? (-2.0f / 4096.0f)
                            : ((a == b ? 1.0f : 2.0f) / 4096.0f);
    if (g < 2 && b > 63) { b = 63; weight = 0.0f; }   // pad waves: masked

    const float* P = (g == 1) ? Y : X;   // row path (index a), RAW
    const float* Q = (g == 0) ? X : Y;   // col path (index b), RAW

    // per-lane dY cols j=2l, 2l+1, diffed inline from raw rows
    f2 ya[8], yb[8];
    {
        const float* Qb = Q + b * 2048;
        const int j0 = lane << 1;
        const int j2 = (j0 + 2 <= 127) ? j0 + 2 : 127;  // lane63: yb masked
        const float4* A4 = (const float4*)(Qb + j0 * 16);
        const float4* B4 = (const float4*)(Qb + (j0 + 1) * 16);
        const float4* C4 = (const float4*)(Qb + j2 * 16);
#pragma unroll
        for (int q = 0; q < 4; ++q) {
            float4 ra = A4[q], rb = B4[q], rc = C4[q];
            ya[2*q].x   = rb.x - ra.x;  ya[2*q].y   = rb.y - ra.y;
            ya[2*q+1].x = rb.z - ra.z;  ya[2*q+1].y = rb.w - ra.w;
            yb[2*q].x   = rc.x - rb.x;  yb[2*q].y   = rc.y - rb.y;
            yb[2*q+1].x = rc.z - rb.z;  yb[2*q+1].y = rc.w - rb.w;
        }
    }

    // wave-uniform raw-X base -> scalar loads
    const int abase = __builtin_amdgcn_readfirstlane(a * 2048);
    const float4* Ar = (const float4*)(P + abase);

    f2 xa[8], xb[8];
    float qpA, qpB;

    // init: qp = dot(x_0, y) + 1
    load_xrow(xa, Ar, 0);
    {
        f2 s0 = 0.0f, s1 = 0.0f, t0 = 0.0f, t1 = 0.0f;
#pragma unroll
        for (int d = 0; d < 8; d += 2) {
            s0 = __builtin_elementwise_fma(xa[d],   ya[d],   s0);
            s1 = __builtin_elementwise_fma(xa[d+1], ya[d+1], s1);
            t0 = __builtin_elementwise_fma(xa[d],   yb[d],   t0);
            t1 = __builtin_elementwise_fma(xa[d+1], yb[d+1], t1);
        }
        const f2 sA = s0 + s1, sB = t0 + t1;
        qpA = (sA.x + sA.y) + 1.0f;
        qpB = (sB.x + sB.y) + 1.0f;
    }
    load_xrow(xa, Ar, 1);

    float g_lo = 1.0f, g_hi = 1.0f;
    // rows 0..125 in pairs; entering iter r, xa holds x_{r+1}
    for (int r = 0; r < 126; r += 2) {
        load_xrow(xb, Ar, r + 2);
        pde_row(xa, ya, yb, qpA, qpB, g_lo, g_hi, lane);   // row r
        load_xrow(xa, Ar, r + 3);
        pde_row(xb, ya, yb, qpA, qpB, g_lo, g_hi, lane);   // row r+1
    }
    pde_row(xa, ya, yb, qpA, qpB, g_lo, g_hi, lane);       // row 126 (x_127)

    const float kab = __builtin_bit_cast(float,
        __builtin_amdgcn_readlane(__builtin_bit_cast(int, g_lo), 63));
    if (lane == 0) red[wv] = weight * kab;
    __syncthreads();
    if (threadIdx.x == 0)
        atomicAdd(outp, (red[0] + red[1]) + (red[2] + red[3]));
}

extern "C" void kernel_launch(void* const* d_in, const int* in_sizes, int n_in,
                              void* d_out, int out_size, void* d_ws, size_t ws_size,
                              hipStream_t stream) {
    const float* X = (const float*)d_in[0];
    const float* Y = (const float*)d_in[1];
    float* out = (float*)d_out;
    (void)d_ws; (void)ws_size; (void)in_sizes; (void)n_in; (void)out_size;

    hipMemsetAsync(d_out, 0, sizeof(float), stream);   // capturable memset node
    sig_pde4<<<NBLOCKS, 256, 0, stream>>>(X, Y, out);
}